// Round 3
// baseline (529.569 us; speedup 1.0000x reference)
//
#include <hip/hip_runtime.h>
#include <cstdio>

// B=64, NN=17, T=128, H=256.
// d_out = outputs [64,17,128,256] fp32 ++ A [64,17,128,128] fp32.
//
// We = Wq^T@Wb@Wk; qWk = node@We; S = qWk@kv^T + b[s]; A = softmax_s(S); out = A@V.
// R3: k_vt computes V transposed (Vt[bn][h][s] bf16), kv read once per block,
//     Wv as bf16 from global (L2-hot). k_fused phase 2 reads Vt direct from
//     global (no LDS stage, no phase-2 barriers); LDS 34.8 KB -> 4 blocks/CU.
//     QK staging unpadded [128][32] (even bank distribution for b128 reads).

typedef __bf16 bf16;
typedef __attribute__((ext_vector_type(8))) __bf16 bf16x8;
typedef __attribute__((ext_vector_type(4))) float floatx4;

#define MFMA_BF16 __builtin_amdgcn_mfma_f32_16x16x32_bf16

__device__ __forceinline__ const float* kv_row_ptr(const float* node, const float* neigh, int bn, int s) {
  int b = bn / 17, nn = bn % 17;
  return (nn == 0) ? node + ((size_t)b * 128 + s) * 256
                   : neigh + (((size_t)b * 16 + (nn - 1)) * 128 + s) * 256;
}

// ---------- K0a: Wc = Wq^T @ Wb ----------
__global__ __launch_bounds__(256) void k_wc(const float* __restrict__ Wq, const float* __restrict__ Wb,
                                            float* __restrict__ Wc) {
  int m = blockIdx.x, h = threadIdx.x;
  float acc = 0.f;
  for (int k = 0; k < 256; ++k) acc = fmaf(Wq[k * 256 + m], Wb[k * 256 + h], acc);
  Wc[m * 256 + h] = acc;
}

// ---------- K0b: We = Wc @ Wk ----------
__global__ __launch_bounds__(256) void k_we(const float* __restrict__ Wc, const float* __restrict__ Wk,
                                            float* __restrict__ We) {
  int m = blockIdx.x, g = threadIdx.x;
  float acc = 0.f;
  for (int k = 0; k < 256; ++k) acc = fmaf(Wc[m * 256 + k], Wk[k * 256 + g], acc);
  We[m * 256 + g] = acc;
}

// ---------- K0c: Wvb = bf16(Wv) ----------
__global__ __launch_bounds__(256) void k_wvb(const float* __restrict__ Wv, bf16* __restrict__ Wvb) {
  int i = (blockIdx.x * 256 + threadIdx.x) * 4;
  float4 v = *(const float4*)(Wv + i);
  bf16 o0 = (bf16)v.x, o1 = (bf16)v.y, o2 = (bf16)v.z, o3 = (bf16)v.w;
  typedef __attribute__((ext_vector_type(4))) __bf16 bf16x4;
  bf16x4 o = {o0, o1, o2, o3};
  *(bf16x4*)(Wvb + i) = o;
}

// ---------- K1: qWk = node @ We; M=8192,N=256,K=256 fp32 ----------
__global__ __launch_bounds__(256) void k_qwk(const float* __restrict__ X, const float* __restrict__ W,
                                             float* __restrict__ Y) {
  __shared__ float As[32][64];
  __shared__ float Bs[32][64];
  int tid = threadIdx.x;
  int m0 = blockIdx.x * 64, n0 = blockIdx.y * 64;
  int tx = tid & 15, ty = tid >> 4;
  float acc[4][4] = {};
  int r = tid >> 3, c4 = (tid & 7) * 4;
  int kr = tid >> 4, c4b = (tid & 15) * 4;
  for (int k0 = 0; k0 < 256; k0 += 32) {
#pragma unroll
    for (int p = 0; p < 2; ++p) {
      float4 v = *(const float4*)(X + (size_t)(m0 + r + p * 32) * 256 + k0 + c4);
      As[c4 + 0][r + p * 32] = v.x; As[c4 + 1][r + p * 32] = v.y;
      As[c4 + 2][r + p * 32] = v.z; As[c4 + 3][r + p * 32] = v.w;
    }
#pragma unroll
    for (int p = 0; p < 2; ++p) {
      float4 v = *(const float4*)(W + (size_t)(k0 + kr + p * 16) * 256 + n0 + c4b);
      *(float4*)&Bs[kr + p * 16][c4b] = v;
    }
    __syncthreads();
#pragma unroll 8
    for (int k = 0; k < 32; ++k) {
      float a[4], bb[4];
#pragma unroll
      for (int i = 0; i < 4; ++i) a[i] = As[k][ty * 4 + i];
#pragma unroll
      for (int j = 0; j < 4; ++j) bb[j] = Bs[k][tx * 4 + j];
#pragma unroll
      for (int i = 0; i < 4; ++i)
#pragma unroll
        for (int j = 0; j < 4; ++j) acc[i][j] = fmaf(a[i], bb[j], acc[i][j]);
    }
    __syncthreads();
  }
#pragma unroll
  for (int i = 0; i < 4; ++i) {
    float4 v = make_float4(acc[i][0], acc[i][1], acc[i][2], acc[i][3]);
    *(float4*)(Y + (size_t)(m0 + ty * 4 + i) * 256 + n0 + tx * 4) = v;
  }
}

// ---------- K2: Vt[h][s] = sum_g Wv[h][g] * kv[s][g]; bf16 MFMA, kv read once ----------
// grid 2176: bn = bx>>1, s-half = (bx&1)*64. Wave w owns h-rows w*64..+63.
#define KVS 264  // bf16 stride: 132 dwords -> bank = 4(r+q)+d, even; 16B-aligned rows
__global__ __launch_bounds__(256, 4) void k_vt(const float* __restrict__ node, const float* __restrict__ neigh,
                                               const bf16* __restrict__ Wvb, bf16* __restrict__ Vt) {
  __shared__ bf16 kvs[64 * KVS];
  int tid = threadIdx.x;
  int w = tid >> 6, lane = tid & 63, lrow = lane & 15, quad = lane >> 4;
  int bn = blockIdx.x >> 1, s0 = (blockIdx.x & 1) * 64;
  const float* src = kv_row_ptr(node, neigh, bn, s0);

  // stage kv[s0..s0+63][0..255] -> bf16 LDS (each thread: one row-quarter = 64 cols)
  {
    int srow = tid >> 2, cseg = (tid & 3) * 64;
    const float* p = src + (size_t)srow * 256 + cseg;
#pragma unroll
    for (int c = 0; c < 8; ++c) {
      float4 a = *(const float4*)(p + c * 8);
      float4 b = *(const float4*)(p + c * 8 + 4);
      bf16x8 o = {(bf16)a.x, (bf16)a.y, (bf16)a.z, (bf16)a.w,
                  (bf16)b.x, (bf16)b.y, (bf16)b.z, (bf16)b.w};
      *(bf16x8*)&kvs[srow * KVS + cseg + c * 8] = o;
    }
  }
  __syncthreads();

  floatx4 acc[4][4];
#pragma unroll
  for (int rt = 0; rt < 4; ++rt)
#pragma unroll
    for (int ct = 0; ct < 4; ++ct) acc[rt][ct] = (floatx4)0.0f;

  for (int k0 = 0; k0 < 256; k0 += 32) {
    bf16x8 bs[4], at[4];
#pragma unroll
    for (int ct = 0; ct < 4; ++ct)
      bs[ct] = *(const bf16x8*)&kvs[(ct * 16 + lrow) * KVS + k0 + quad * 8];
#pragma unroll
    for (int rt = 0; rt < 4; ++rt)
      at[rt] = *(const bf16x8*)&Wvb[(size_t)(w * 64 + rt * 16 + lrow) * 256 + k0 + quad * 8];
#pragma unroll
    for (int rt = 0; rt < 4; ++rt)
#pragma unroll
      for (int ct = 0; ct < 4; ++ct)
        acc[rt][ct] = MFMA_BF16(at[rt], bs[ct], acc[rt][ct], 0, 0, 0);
  }

  bf16* out = Vt + (size_t)bn * 32768;
#pragma unroll
  for (int rt = 0; rt < 4; ++rt)
#pragma unroll
    for (int ct = 0; ct < 4; ++ct)
#pragma unroll
      for (int rg = 0; rg < 4; ++rg) {
        int h = w * 64 + rt * 16 + quad * 4 + rg;
        int s = s0 + ct * 16 + lrow;
        out[h * 128 + s] = (bf16)acc[rt][ct][rg];
      }
}

// ---------- K3 fused: S=qWk@kv^T (hi/lo bf16 MFMA) + bias + softmax -> A; out = A@Vt ----------
// one block per bn; 4 waves; wave w owns rows w*32..+31.
#define ABS 136  // bf16 stride for Ab: 68 dw -> bank = 4(r+q)+d, even
__global__ __launch_bounds__(256, 4) void k_fused(const float* __restrict__ qWk, const float* __restrict__ node,
                                                  const float* __restrict__ neigh, const float* __restrict__ bvec,
                                                  const bf16* __restrict__ Vt,
                                                  float* __restrict__ Aout, float* __restrict__ Out) {
  __shared__ __align__(16) char smem[34816];
  bf16* Qhi = (bf16*)smem;               // [128][32]
  bf16* Qlo = (bf16*)(smem + 8192);
  bf16* Khi = (bf16*)(smem + 16384);
  bf16* Klo = (bf16*)(smem + 24576);
  bf16* Ab  = (bf16*)smem;               // [128][ABS], phase 2 (aliases phase-1 bufs)

  int tid = threadIdx.x;
  int w = tid >> 6, lane = tid & 63, lrow = lane & 15, quad = lane >> 4;
  int bn = blockIdx.x;
  const float* Q = qWk + (size_t)(bn / 17) * 128 * 256;
  const float* K = kv_row_ptr(node, neigh, bn, 0);

  int srow = tid >> 1;            // staging row 0..127
  int skb = (tid & 1) * 16;       // staging k base 0 or 16

  floatx4 acc[2][8];
#pragma unroll
  for (int rt = 0; rt < 2; ++rt)
#pragma unroll
    for (int ct = 0; ct < 8; ++ct) acc[rt][ct] = (floatx4)0.0f;

  // ---- phase 1: S = Q @ K^T via 3-term hi/lo split ----
  for (int k0 = 0; k0 < 256; k0 += 32) {
#pragma unroll
    for (int half = 0; half < 2; ++half) {
      const float* qp = Q + (size_t)srow * 256 + k0 + skb + half * 8;
      const float* kp = K + (size_t)srow * 256 + k0 + skb + half * 8;
      float4 q0 = *(const float4*)qp, q1 = *(const float4*)(qp + 4);
      float4 kk0 = *(const float4*)kp, kk1 = *(const float4*)(kp + 4);
      float qf[8] = {q0.x, q0.y, q0.z, q0.w, q1.x, q1.y, q1.z, q1.w};
      float kf[8] = {kk0.x, kk0.y, kk0.z, kk0.w, kk1.x, kk1.y, kk1.z, kk1.w};
      bf16x8 qh, ql, kh, kl;
#pragma unroll
      for (int u = 0; u < 8; ++u) {
        bf16 h = (bf16)qf[u]; qh[u] = h; ql[u] = (bf16)(qf[u] - (float)h);
        bf16 h2 = (bf16)kf[u]; kh[u] = h2; kl[u] = (bf16)(kf[u] - (float)h2);
      }
      int off = srow * 32 + skb + half * 8;
      *(bf16x8*)&Qhi[off] = qh; *(bf16x8*)&Qlo[off] = ql;
      *(bf16x8*)&Khi[off] = kh; *(bf16x8*)&Klo[off] = kl;
    }
    __syncthreads();
    bf16x8 ah[2], al[2];
#pragma unroll
    for (int rt = 0; rt < 2; ++rt) {
      int off = (w * 32 + rt * 16 + lrow) * 32 + quad * 8;
      ah[rt] = *(const bf16x8*)&Qhi[off];
      al[rt] = *(const bf16x8*)&Qlo[off];
    }
#pragma unroll
    for (int ct = 0; ct < 8; ++ct) {
      int off = (ct * 16 + lrow) * 32 + quad * 8;
      bf16x8 bh = *(const bf16x8*)&Khi[off];
      bf16x8 bl = *(const bf16x8*)&Klo[off];
#pragma unroll
      for (int rt = 0; rt < 2; ++rt) {
        acc[rt][ct] = MFMA_BF16(ah[rt], bh, acc[rt][ct], 0, 0, 0);
        acc[rt][ct] = MFMA_BF16(al[rt], bh, acc[rt][ct], 0, 0, 0);
        acc[rt][ct] = MFMA_BF16(ah[rt], bl, acc[rt][ct], 0, 0, 0);
      }
    }
    __syncthreads();  // trailing sync also protects staging bufs before Ab overwrite
  }

  // ---- softmax over s (per row), in registers ----
  float bvv[8];
#pragma unroll
  for (int ct = 0; ct < 8; ++ct) bvv[ct] = bvec[ct * 16 + lrow];
#pragma unroll
  for (int rt = 0; rt < 2; ++rt)
#pragma unroll
    for (int r = 0; r < 4; ++r) {
      float mx = -3.402823466e+38f;
#pragma unroll
      for (int ct = 0; ct < 8; ++ct) {
        float v = acc[rt][ct][r] + bvv[ct];
        acc[rt][ct][r] = v;
        mx = fmaxf(mx, v);
      }
#pragma unroll
      for (int off = 1; off < 16; off <<= 1) mx = fmaxf(mx, __shfl_xor(mx, off, 64));
      float s = 0.f;
#pragma unroll
      for (int ct = 0; ct < 8; ++ct) {
        float e = __expf(acc[rt][ct][r] - mx);
        acc[rt][ct][r] = e;
        s += e;
      }
#pragma unroll
      for (int off = 1; off < 16; off <<= 1) s += __shfl_xor(s, off, 64);
      float inv = 1.f / s;
#pragma unroll
      for (int ct = 0; ct < 8; ++ct) acc[rt][ct][r] *= inv;
    }

  // ---- write A (global fp32) + Ab (LDS bf16, A-operand layout; own-wave rows only) ----
  float* Ag = Aout + (size_t)bn * 128 * 128;
#pragma unroll
  for (int rt = 0; rt < 2; ++rt)
#pragma unroll
    for (int r = 0; r < 4; ++r) {
      int row = w * 32 + rt * 16 + quad * 4 + r;
#pragma unroll
      for (int ct = 0; ct < 8; ++ct) {
        int s = ct * 16 + lrow;
        float v = acc[rt][ct][r];
        Ag[(size_t)row * 128 + s] = v;
        Ab[row * ABS + s] = (bf16)v;
      }
    }

  // ---- phase 2: out = A @ V via Vt (global, L2-hot); no barriers ----
  const bf16* Vb = Vt + (size_t)bn * 32768;
  float* Ob = Out + (size_t)bn * 128 * 256;
  for (int h0 = 0; h0 < 256; h0 += 64) {
    floatx4 pacc[2][4];
#pragma unroll
    for (int rt = 0; rt < 2; ++rt)
#pragma unroll
      for (int ct = 0; ct < 4; ++ct) pacc[rt][ct] = (floatx4)0.0f;
#pragma unroll
    for (int sk = 0; sk < 128; sk += 32) {
      bf16x8 af[2];
#pragma unroll
      for (int rt = 0; rt < 2; ++rt)
        af[rt] = *(const bf16x8*)&Ab[(w * 32 + rt * 16 + lrow) * ABS + sk + quad * 8];
#pragma unroll
      for (int ct = 0; ct < 4; ++ct) {
        bf16x8 bv8 = *(const bf16x8*)&Vb[(size_t)(h0 + ct * 16 + lrow) * 128 + sk + quad * 8];
#pragma unroll
        for (int rt = 0; rt < 2; ++rt)
          pacc[rt][ct] = MFMA_BF16(af[rt], bv8, pacc[rt][ct], 0, 0, 0);
      }
    }
#pragma unroll
    for (int rt = 0; rt < 2; ++rt)
#pragma unroll
      for (int ct = 0; ct < 4; ++ct)
#pragma unroll
        for (int r = 0; r < 4; ++r) {
          int row = w * 32 + rt * 16 + quad * 4 + r;
          Ob[(size_t)row * 256 + h0 + ct * 16 + lrow] = pacc[rt][ct][r];
        }
  }
}

extern "C" void kernel_launch(void* const* d_in, const int* in_sizes, int n_in,
                              void* d_out, int out_size, void* d_ws, size_t ws_size,
                              hipStream_t stream) {
  const float* node  = (const float*)d_in[0];
  const float* neigh = (const float*)d_in[1];
  const float* Wq = (const float*)d_in[3];
  const float* Wk = (const float*)d_in[4];
  const float* Wv = (const float*)d_in[5];
  const float* Wb = (const float*)d_in[6];
  const float* bv = (const float*)d_in[7];

  float* out  = (float*)d_out;
  float* Aout = out + (size_t)64 * 17 * 128 * 256;

  // ws: Wc(64K f32) | We(64K f32) | qWk(2M f32) | Wvb(64K bf16) | Vt(34.8M bf16)
  size_t need = (size_t)(65536 + 65536 + 2097152) * 4 + (size_t)65536 * 2 + (size_t)35651584 * 2;
  if (ws_size < need) { fprintf(stderr, "ws too small: %zu < %zu\n", ws_size, need); return; }
  float* wsf = (float*)d_ws;
  float* Wc  = wsf;
  float* We  = wsf + 65536;
  float* qWk = wsf + 131072;
  bf16*  Wvb = (bf16*)(wsf + 131072 + 2097152);
  bf16*  Vt  = Wvb + 65536;

  k_wc<<<256, 256, 0, stream>>>(Wq, Wb, Wc);
  k_wvb<<<64, 256, 0, stream>>>(Wv, Wvb);
  k_we<<<256, 256, 0, stream>>>(Wc, Wk, We);
  k_qwk<<<dim3(128, 4), 256, 0, stream>>>(node, We, qWk);
  k_vt<<<2176, 256, 0, stream>>>(node, neigh, Wvb, Vt);
  k_fused<<<1088, 256, 0, stream>>>(qWk, node, neigh, bv, Vt, Aout, out);
}